// Round 2
// baseline (1450.128 us; speedup 1.0000x reference)
//
#include <hip/hip_runtime.h>
#include <hip/hip_bf16.h>

typedef __bf16 bf16x8 __attribute__((ext_vector_type(8)));
typedef float f32x4 __attribute__((ext_vector_type(4)));

#define HIDDEN 4096
#define NH 32
#define HD 128
#define SEQ 2048
#define BATCH 2
#define MTOT 4096           // BATCH*SEQ
#define QKV 12288

// ---- async global->LDS, 16B per lane; LDS dest = wave-uniform base + lane*16 ----
__device__ __forceinline__ void async16(const void* g, void* l) {
    __builtin_amdgcn_global_load_lds(
        (const __attribute__((address_space(1))) void*)(uintptr_t)g,
        (__attribute__((address_space(3))) void*)(uint32_t)(uintptr_t)l,
        16, 0, 0);
}

// Load 8 source elements and return them as 8 packed bf16 (one uint4).
__device__ __forceinline__ uint4 ld8(const __hip_bfloat16* p) { return *(const uint4*)p; }
__device__ __forceinline__ uint4 ld8(const float* p) {
    float4 a = *(const float4*)p;
    float4 b = *(const float4*)(p + 4);
    __hip_bfloat16 t[8];
    t[0] = __float2bfloat16(a.x); t[1] = __float2bfloat16(a.y);
    t[2] = __float2bfloat16(a.z); t[3] = __float2bfloat16(a.w);
    t[4] = __float2bfloat16(b.x); t[5] = __float2bfloat16(b.y);
    t[6] = __float2bfloat16(b.z); t[7] = __float2bfloat16(b.w);
    return *(uint4*)t;
}

__device__ __forceinline__ void stc(__hip_bfloat16* C, size_t i, float v) { C[i] = __float2bfloat16(v); }
__device__ __forceinline__ void stc(float* C, size_t i, float v) { C[i] = v; }

// fp32 -> bf16 bulk convert, 8 elems/thread.
__global__ __launch_bounds__(256) void cvt_bf16(const float* __restrict__ src,
                                                __hip_bfloat16* __restrict__ dst, int n8) {
    int i = blockIdx.x * 256 + threadIdx.x;
    if (i < n8) *(uint4*)&dst[(size_t)i * 8] = ld8(&src[(size_t)i * 8]);
}

// m97-style GEMM: C[M,N] = A[M,K] @ Bt[N,K]^T, bf16 in, fp32 MFMA acc.
// 128x128 tile, BK=32, staging via global_load_lds width=16 (2+2 insts/wave).
template <typename TC>
__global__ __launch_bounds__(256) void gemm_lds(const __hip_bfloat16* __restrict__ A,
                                                const __hip_bfloat16* __restrict__ Bt,
                                                TC* __restrict__ C,
                                                int M, int N, int K, int lda) {
    __shared__ __align__(16) __hip_bfloat16 As[128][32];
    __shared__ __align__(16) __hip_bfloat16 Bs[128][32];
    const int bn = blockIdx.x * 128, bm = blockIdx.y * 128;
    const int tid = threadIdx.x, wave = tid >> 6, lane = tid & 63;
    const int wm = (wave >> 1) * 64, wn = (wave & 1) * 64;
    const int row16 = lane & 15, quad = lane >> 4;
    const int lr = lane >> 2;          // 0..15: row within a 16-row chunk
    const int lc = (lane & 3) * 8;     // 0,8,16,24: col chunk
    // per-lane global addrs; LDS dests are wave-uniform (+lane*16 implicit)
    const __hip_bfloat16* Ab = A + (size_t)(bm + wave * 32 + lr) * lda + lc;
    const __hip_bfloat16* Bb = Bt + (size_t)(bn + wave * 32 + lr) * K + lc;

    f32x4 acc[4][4] = {};

    for (int kt = 0; kt < K; kt += 32) {
        __syncthreads();
        async16(Ab + kt,                   &As[wave * 32][0]);
        async16(Ab + (size_t)16 * lda + kt, &As[wave * 32 + 16][0]);
        async16(Bb + kt,                   &Bs[wave * 32][0]);
        async16(Bb + (size_t)16 * K + kt,  &Bs[wave * 32 + 16][0]);
        __syncthreads();
        bf16x8 af[4], bf[4];
#pragma unroll
        for (int i = 0; i < 4; ++i) af[i] = *(const bf16x8*)&As[wm + i * 16 + row16][quad * 8];
#pragma unroll
        for (int j = 0; j < 4; ++j) bf[j] = *(const bf16x8*)&Bs[wn + j * 16 + row16][quad * 8];
#pragma unroll
        for (int i = 0; i < 4; ++i)
#pragma unroll
            for (int j = 0; j < 4; ++j)
                acc[i][j] = __builtin_amdgcn_mfma_f32_16x16x32_bf16(af[i], bf[j], acc[i][j], 0, 0, 0);
    }
    const int col0 = bn + wn + row16;
    const int row0 = bm + wm + quad * 4;
#pragma unroll
    for (int i = 0; i < 4; ++i)
#pragma unroll
        for (int j = 0; j < 4; ++j)
#pragma unroll
            for (int rg = 0; rg < 4; ++rg)
                stc(C, (size_t)(row0 + i * 16 + rg) * N + col0 + j * 16, acc[i][j][rg]);
}

// Fallback GEMM (fp32 or bf16 inputs via ld8 staging). Used when ws is small.
template <typename TA, typename TB, typename TC>
__global__ __launch_bounds__(256) void gemm_bt(const TA* __restrict__ A,
                                               const TB* __restrict__ Bt,
                                               TC* __restrict__ C,
                                               int M, int N, int K, int lda) {
    __shared__ __align__(16) __hip_bfloat16 As[128][32];
    __shared__ __align__(16) __hip_bfloat16 Bs[128][32];
    const int bn = blockIdx.x * 128, bm = blockIdx.y * 128;
    const int tid = threadIdx.x, wave = tid >> 6, lane = tid & 63;
    const int wm = (wave >> 1) * 64, wn = (wave & 1) * 64;
    const int row16 = lane & 15, quad = lane >> 4;
    const int arow = tid >> 2;
    const int acol = (tid & 3) * 8;

    f32x4 acc[4][4] = {};

    for (int kt = 0; kt < K; kt += 32) {
        __syncthreads();
#pragma unroll
        for (int it = 0; it < 2; ++it) {
            int r = arow + it * 64;
            *(uint4*)&As[r][acol] = ld8(&A[(size_t)(bm + r) * lda + kt + acol]);
            *(uint4*)&Bs[r][acol] = ld8(&Bt[(size_t)(bn + r) * K + kt + acol]);
        }
        __syncthreads();
        bf16x8 af[4], bf[4];
#pragma unroll
        for (int i = 0; i < 4; ++i) af[i] = *(const bf16x8*)&As[wm + i * 16 + row16][quad * 8];
#pragma unroll
        for (int j = 0; j < 4; ++j) bf[j] = *(const bf16x8*)&Bs[wn + j * 16 + row16][quad * 8];
#pragma unroll
        for (int i = 0; i < 4; ++i)
#pragma unroll
            for (int j = 0; j < 4; ++j)
                acc[i][j] = __builtin_amdgcn_mfma_f32_16x16x32_bf16(af[i], bf[j], acc[i][j], 0, 0, 0);
    }
    const int col0 = bn + wn + row16;
    const int row0 = bm + wm + quad * 4;
#pragma unroll
    for (int i = 0; i < 4; ++i)
#pragma unroll
        for (int j = 0; j < 4; ++j)
#pragma unroll
            for (int rg = 0; rg < 4; ++rg)
                stc(C, (size_t)(row0 + i * 16 + rg) * N + col0 + j * 16, acc[i][j][rg]);
}

// In-place RoPE on the Q and K thirds of proj[MTOT][QKV]. position = row % SEQ.
// Q rows additionally pre-scaled by 1/sqrt(HD) so attn skips the score scaling.
__global__ __launch_bounds__(256) void rope_kernel(__hip_bfloat16* __restrict__ proj) {
    int t = blockIdx.x * 256 + threadIdx.x;
    int j = t & 63;
    int head = (t >> 6) & 31;
    int mat = (t >> 11) & 1;
    int row = t >> 12;
    int pos = row & (SEQ - 1);
    float invf = __expf(-(float)j * 0.14391156514261f);   // 10000^(-j/64)
    float ang = (float)pos * invf;
    float rev = ang * 0.15915494309189535f;               // range-reduce for v_sin/v_cos
    rev -= floorf(rev);
    float arad = rev * 6.283185307179586f;
    float sn = __sinf(arad);
    float cs = __cosf(arad);
    if (mat == 0) {                     // Q third: fold in 1/sqrt(128)
        sn *= 0.08838834764831845f;
        cs *= 0.08838834764831845f;
    }
    size_t base = (size_t)row * QKV + mat * HIDDEN + head * HD + j;
    float x1 = __bfloat162float(proj[base]);
    float x2 = __bfloat162float(proj[base + 64]);
    proj[base]      = __float2bfloat16(x1 * cs - x2 * sn);
    proj[base + 64] = __float2bfloat16(x2 * cs + x1 * sn);
}

// One-shot V transpose: proj V-third [b][s][h*128+d] -> vtg[(b*32+h)][d][s].
__global__ __launch_bounds__(256) void transpose_v(const __hip_bfloat16* __restrict__ proj,
                                                   __hip_bfloat16* __restrict__ vtg) {
    __shared__ __hip_bfloat16 Ls[64][132];
    const int st = blockIdx.x, bh = blockIdx.y;
    const int b = bh >> 5, h = bh & 31;
    const int s0 = st << 6;
    const int tid = threadIdx.x;
    const __hip_bfloat16* vb = proj + (size_t)b * SEQ * QKV + 2 * HIDDEN + h * HD;
    for (int i = tid; i < 1024; i += 256) {
        int r = i >> 4, c = (i & 15) << 3;
        uint4 raw = *(const uint4*)&vb[(size_t)(s0 + r) * QKV + c];
        *(uint2*)&Ls[r][c]     = make_uint2(raw.x, raw.y);
        *(uint2*)&Ls[r][c + 4] = make_uint2(raw.z, raw.w);
    }
    __syncthreads();
    __hip_bfloat16* ob = vtg + (size_t)bh * HD * SEQ + s0;
    for (int t = tid; t < 1024; t += 256) {
        int d = t >> 3, sc = (t & 7) << 3;
        __hip_bfloat16 tmp[8];
#pragma unroll
        for (int x = 0; x < 8; ++x) tmp[x] = Ls[sc + x][d];
        *(uint4*)&ob[(size_t)d * SEQ + sc] = *(uint4*)tmp;
    }
}

// MFMA flash attention. Block = 128 q-rows x (b,h); 4 waves x 32 q-rows each.
// Requires gridDim.x == SEQ/128 == 16. Two barriers per 64-key tile; the Ps
// LDS buffer is strictly per-wave so no barrier is needed between its write
// and read (in-wave LDS DS ops execute in program order).
__global__ __launch_bounds__(256) void attn_mfma(__hip_bfloat16* __restrict__ proj,
                                                 const __hip_bfloat16* __restrict__ vtg) {
    __shared__ __align__(16) __hip_bfloat16 Ks[64][136];   // 64 keys x 128 d
    __shared__ __align__(16) __hip_bfloat16 Vs[128][72];   // 128 d x 64 keys
    __shared__ __align__(16) __hip_bfloat16 Ps[4][32][72]; // per-wave P tile
    // XCD-chunked swizzle (bijective: nwg=1024, %8==0): each XCD owns 8 whole
    // heads so the active head's K/V (1 MB) stays resident in its 4 MiB L2.
    const int nwg = gridDim.x * gridDim.y;
    const int f  = blockIdx.y * gridDim.x + blockIdx.x;
    const int f2 = (f & 7) * (nwg >> 3) + (f >> 3);
    const int qt = f2 & 15;            // gridDim.x == 16
    const int bh = f2 >> 4;
    const int b = bh >> 5, h = bh & 31;
    const int q0 = qt << 7;
    const int tid = threadIdx.x, wave = tid >> 6, lane = tid & 63;
    const int row16 = lane & 15, quad = lane >> 4;

    __hip_bfloat16* qb = proj + (size_t)b * SEQ * QKV + h * HD;
    const __hip_bfloat16* kb = qb + HIDDEN;
    const __hip_bfloat16* vp = vtg + (size_t)bh * HD * SEQ;

    const int wbase = q0 + wave * 32;

    bf16x8 qf[2][4];
#pragma unroll
    for (int qr = 0; qr < 2; ++qr) {
        const __hip_bfloat16* qrow = qb + (size_t)(wbase + qr * 16 + row16) * QKV + quad * 8;
#pragma unroll
        for (int s = 0; s < 4; ++s) qf[qr][s] = *(const bf16x8*)(qrow + s * 32);
    }

    f32x4 oa[2][8] = {};
    float m_i[2][4], l_i[2][4];
#pragma unroll
    for (int qr = 0; qr < 2; ++qr)
#pragma unroll
        for (int r = 0; r < 4; ++r) { m_i[qr][r] = -3.0e38f; l_i[qr][r] = 0.f; }

    const int ktmax = 2 * qt + 1;
    for (int kt = 0; kt <= ktmax; ++kt) {
        const int k0 = kt << 6;
        __syncthreads();
        for (int i = tid; i < 1024; i += 256) {
            int r = i >> 4, c = (i & 15) << 3;
            *(uint4*)&Ks[r][c] = *(const uint4*)&kb[(size_t)(k0 + r) * QKV + c];
        }
        for (int i = tid; i < 1024; i += 256) {
            int d = i >> 3, ko = (i & 7) << 3;
            *(uint4*)&Vs[d][ko] = *(const uint4*)&vp[(size_t)d * SEQ + k0 + ko];
        }
        __syncthreads();
        // Both barriers of this iteration are done; waves whose 32 rows are
        // entirely above this key tile skip the compute (wave-uniform).
        if (k0 > wbase + 31) continue;

        // S = Q K^T  (Q pre-scaled by 1/sqrt(d) in rope_kernel)
        f32x4 sf[2][4] = {};
#pragma unroll
        for (int nt = 0; nt < 4; ++nt) {
            bf16x8 kf[4];
#pragma unroll
            for (int ks = 0; ks < 4; ++ks)
                kf[ks] = *(const bf16x8*)&Ks[nt * 16 + row16][ks * 32 + quad * 8];
#pragma unroll
            for (int qr = 0; qr < 2; ++qr)
#pragma unroll
                for (int ks = 0; ks < 4; ++ks)
                    sf[qr][nt] = __builtin_amdgcn_mfma_f32_16x16x32_bf16(qf[qr][ks], kf[ks], sf[qr][nt], 0, 0, 0);
        }
        if (k0 + 63 > wbase) {          // diagonal region: causal mask
#pragma unroll
            for (int qr = 0; qr < 2; ++qr)
#pragma unroll
                for (int nt = 0; nt < 4; ++nt) {
                    int key = k0 + nt * 16 + row16;
#pragma unroll
                    for (int rg = 0; rg < 4; ++rg)
                        if (key > wbase + qr * 16 + quad * 4 + rg) sf[qr][nt][rg] = -3.0e38f;
                }
        }
        // online softmax, per 16-row fragment
#pragma unroll
        for (int qr = 0; qr < 2; ++qr) {
            float alpha[4], rs[4];
#pragma unroll
            for (int rg = 0; rg < 4; ++rg) {
                float mx = fmaxf(fmaxf(sf[qr][0][rg], sf[qr][1][rg]), fmaxf(sf[qr][2][rg], sf[qr][3][rg]));
#pragma unroll
                for (int off = 8; off > 0; off >>= 1) mx = fmaxf(mx, __shfl_xor(mx, off));
                float mn = fmaxf(m_i[qr][rg], mx);
                alpha[rg] = __expf(m_i[qr][rg] - mn);
                m_i[qr][rg] = mn;
                rs[rg] = 0.f;
            }
#pragma unroll
            for (int nt = 0; nt < 4; ++nt)
#pragma unroll
                for (int rg = 0; rg < 4; ++rg) {
                    float p = __expf(sf[qr][nt][rg] - m_i[qr][rg]);
                    rs[rg] += p;
                    Ps[wave][qr * 16 + quad * 4 + rg][nt * 16 + row16] = __float2bfloat16(p);
                }
#pragma unroll
            for (int rg = 0; rg < 4; ++rg) {
#pragma unroll
                for (int off = 8; off > 0; off >>= 1) rs[rg] += __shfl_xor(rs[rg], off);
                l_i[qr][rg] = l_i[qr][rg] * alpha[rg] + rs[rg];
            }
#pragma unroll
            for (int dt = 0; dt < 8; ++dt)
#pragma unroll
                for (int rg = 0; rg < 4; ++rg) oa[qr][dt][rg] *= alpha[rg];
        }
        __builtin_amdgcn_wave_barrier();   // compile-time order: Ps writes before reads
        bf16x8 pf[2][2];
#pragma unroll
        for (int qr = 0; qr < 2; ++qr) {
            pf[qr][0] = *(const bf16x8*)&Ps[wave][qr * 16 + row16][quad * 8];
            pf[qr][1] = *(const bf16x8*)&Ps[wave][qr * 16 + row16][32 + quad * 8];
        }
#pragma unroll
        for (int dt = 0; dt < 8; ++dt) {
            bf16x8 v0 = *(const bf16x8*)&Vs[dt * 16 + row16][quad * 8];
            bf16x8 v1 = *(const bf16x8*)&Vs[dt * 16 + row16][32 + quad * 8];
#pragma unroll
            for (int qr = 0; qr < 2; ++qr) {
                oa[qr][dt] = __builtin_amdgcn_mfma_f32_16x16x32_bf16(pf[qr][0], v0, oa[qr][dt], 0, 0, 0);
                oa[qr][dt] = __builtin_amdgcn_mfma_f32_16x16x32_bf16(pf[qr][1], v1, oa[qr][dt], 0, 0, 0);
            }
        }
    }
#pragma unroll
    for (int qr = 0; qr < 2; ++qr)
#pragma unroll
        for (int rg = 0; rg < 4; ++rg) {
            float inv = 1.0f / l_i[qr][rg];
            __hip_bfloat16* orow = qb + (size_t)(wbase + qr * 16 + quad * 4 + rg) * QKV;
#pragma unroll
            for (int dt = 0; dt < 8; ++dt)
                orow[dt * 16 + row16] = __float2bfloat16(oa[qr][dt][rg] * inv);
        }
}

extern "C" void kernel_launch(void* const* d_in, const int* in_sizes, int n_in,
                              void* d_out, int out_size, void* d_ws, size_t ws_size,
                              hipStream_t stream) {
    const float* hs = (const float*)d_in[0];
    const float* Wp = (const float*)d_in[3];
    const float* Wo = (const float*)d_in[4];
    float* out = (float*)d_out;

    const size_t SZ_PROJ = (size_t)MTOT * QKV;      // bf16 elems
    const size_t SZ_H    = (size_t)MTOT * HIDDEN;
    const size_t SZ_WP   = (size_t)QKV * HIDDEN;
    const size_t need = (SZ_PROJ + SZ_H + SZ_WP + SZ_H) * sizeof(__hip_bfloat16);  // 256 MiB

    __hip_bfloat16* proj = (__hip_bfloat16*)d_ws;

    if (ws_size >= need) {
        // [proj][hsb][Wpb][Wob]; vtg aliases the (dead-after-GEMM1) hsb region.
        __hip_bfloat16* hsb = proj + SZ_PROJ;
        __hip_bfloat16* Wpb = hsb + SZ_H;
        __hip_bfloat16* Wob = Wpb + SZ_WP;
        __hip_bfloat16* vtg = hsb;   // 33.6 MB, fits in hsb+Wpb (134 MB)

        cvt_bf16<<<dim3(SZ_H / 8 / 256), dim3(256), 0, stream>>>(hs, hsb, SZ_H / 8);
        cvt_bf16<<<dim3(SZ_WP / 8 / 256), dim3(256), 0, stream>>>(Wp, Wpb, SZ_WP / 8);
        cvt_bf16<<<dim3(SZ_H / 8 / 256), dim3(256), 0, stream>>>(Wo, Wob, SZ_H / 8);
        gemm_lds<<<dim3(QKV / 128, MTOT / 128), dim3(256), 0, stream>>>(hsb, Wpb, proj, MTOT, QKV, HIDDEN, HIDDEN);
        rope_kernel<<<dim3((MTOT * 2 * NH * 64) / 256), dim3(256), 0, stream>>>(proj);
        transpose_v<<<dim3(SEQ / 64, BATCH * NH), dim3(256), 0, stream>>>(proj, vtg);
        attn_mfma<<<dim3(SEQ / 128, BATCH * NH), dim3(256), 0, stream>>>(proj, vtg);
        gemm_lds<<<dim3(HIDDEN / 128, MTOT / 128), dim3(256), 0, stream>>>(proj, Wob, out, MTOT, HIDDEN, HIDDEN, QKV);
    } else {
        // proven 128-MiB fallback (round-4 path)
        __hip_bfloat16* vtg = proj + SZ_PROJ;
        gemm_bt<<<dim3(QKV / 128, MTOT / 128), dim3(256), 0, stream>>>(hs, Wp, proj, MTOT, QKV, HIDDEN, HIDDEN);
        rope_kernel<<<dim3((MTOT * 2 * NH * 64) / 256), dim3(256), 0, stream>>>(proj);
        transpose_v<<<dim3(SEQ / 64, BATCH * NH), dim3(256), 0, stream>>>(proj, vtg);
        attn_mfma<<<dim3(SEQ / 128, BATCH * NH), dim3(256), 0, stream>>>(proj, vtg);
        gemm_bt<<<dim3(HIDDEN / 128, MTOT / 128), dim3(256), 0, stream>>>(proj, Wo, out, MTOT, HIDDEN, HIDDEN, QKV);
    }
}

// Round 3
// 1245.853 us; speedup vs baseline: 1.1640x; 1.1640x over previous
//
#include <hip/hip_runtime.h>
#include <hip/hip_bf16.h>

typedef __bf16 bf16x8 __attribute__((ext_vector_type(8)));
typedef float f32x4 __attribute__((ext_vector_type(4)));

#define HIDDEN 4096
#define NH 32
#define HD 128
#define SEQ 2048
#define BATCH 2
#define MTOT 4096           // BATCH*SEQ
#define QKV 12288

// ---- async global->LDS, 16B per lane; LDS dest = wave-uniform base + lane*16 ----
__device__ __forceinline__ void async16(const void* g, void* l) {
    __builtin_amdgcn_global_load_lds(
        (const __attribute__((address_space(1))) void*)(uintptr_t)g,
        (__attribute__((address_space(3))) void*)(uint32_t)(uintptr_t)l,
        16, 0, 0);
}

// Load 8 source elements and return them as 8 packed bf16 (one uint4).
__device__ __forceinline__ uint4 ld8(const __hip_bfloat16* p) { return *(const uint4*)p; }
__device__ __forceinline__ uint4 ld8(const float* p) {
    float4 a = *(const float4*)p;
    float4 b = *(const float4*)(p + 4);
    __hip_bfloat16 t[8];
    t[0] = __float2bfloat16(a.x); t[1] = __float2bfloat16(a.y);
    t[2] = __float2bfloat16(a.z); t[3] = __float2bfloat16(a.w);
    t[4] = __float2bfloat16(b.x); t[5] = __float2bfloat16(b.y);
    t[6] = __float2bfloat16(b.z); t[7] = __float2bfloat16(b.w);
    return *(uint4*)t;
}

__device__ __forceinline__ void stc(__hip_bfloat16* C, size_t i, float v) { C[i] = __float2bfloat16(v); }
__device__ __forceinline__ void stc(float* C, size_t i, float v) { C[i] = v; }

// fp32 -> bf16 bulk convert, 8 elems/thread.
__global__ __launch_bounds__(256) void cvt_bf16(const float* __restrict__ src,
                                                __hip_bfloat16* __restrict__ dst, int n8) {
    int i = blockIdx.x * 256 + threadIdx.x;
    if (i < n8) *(uint4*)&dst[(size_t)i * 8] = ld8(&src[(size_t)i * 8]);
}

// 256x256-tile GEMM, BK=32, 4-slot LDS ring, counted vmcnt (T3+T4+T5).
// C[M,N] = A[M,K] @ Bt[N,K]^T, bf16 in, fp32 MFMA acc. 8 waves (2M x 4N),
// per-wave output 128x64 (acc[8][4]). One raw s_barrier per K-tile; loads for
// tiles t+1..t+3 stay in flight across it (s_waitcnt vmcnt(8), never 0 in
// the main loop). Requires K >= 96 and M%256==0, N%256==0, K%32==0.
// Race audit: stage(t+3) targets slot (t+3)&3 which held tile t-1; issued
// only after barrier t, which every wave reaches only after finishing its
// tile t-1 reads. vmcnt(8) before barrier t guarantees tile t's own-wave
// loads landed; barrier extends that to all waves.
template <typename TC>
__global__ __launch_bounds__(512) void gemm_256(const __hip_bfloat16* __restrict__ A,
                                                const __hip_bfloat16* __restrict__ Bt,
                                                TC* __restrict__ C,
                                                int M, int N, int K, int lda) {
    __shared__ __align__(16) __hip_bfloat16 As[4][256][32];   // 64 KiB
    __shared__ __align__(16) __hip_bfloat16 Bs[4][256][32];   // 64 KiB
    const int bn = blockIdx.x * 256, bm = blockIdx.y * 256;
    const int tid = threadIdx.x, wave = tid >> 6, lane = tid & 63;
    const int wm = wave >> 2, wn = wave & 3;      // 2 x 4 wave grid
    const int row16 = lane & 15, quad = lane >> 4;
    const int lr = lane >> 2;           // 0..15: row within a 16-row chunk
    const int lc = (lane & 3) * 8;      // 0,8,16,24: col chunk
    const __hip_bfloat16* Ab = A + (size_t)(bm + wave * 16 + lr) * lda + lc;
    const __hip_bfloat16* Bb = Bt + (size_t)(bn + wave * 16 + lr) * K + lc;
    const int NT = K >> 5;

    f32x4 acc[8][4] = {};

    auto stage = [&](int t) {
        const int s = t & 3;
        const int kt = t << 5;
        async16(Ab + kt,                     &As[s][wave * 16][0]);
        async16(Ab + (size_t)128 * lda + kt, &As[s][wave * 16 + 128][0]);
        async16(Bb + kt,                     &Bs[s][wave * 16][0]);
        async16(Bb + (size_t)128 * K + kt,   &Bs[s][wave * 16 + 128][0]);
    };

    stage(0); stage(1); stage(2);       // 12 loads in flight

    for (int t = 0; t < NT; ++t) {
        const int s = t & 3;
        const int rem = NT - 1 - t;
        // Own-wave loads for tile t must have landed; allow 2 tiles (8 loads)
        // to remain outstanding. Epilogue drains 8 -> 4 -> 0.
        if (rem >= 2)      asm volatile("s_waitcnt vmcnt(8)" ::: "memory");
        else if (rem == 1) asm volatile("s_waitcnt vmcnt(4)" ::: "memory");
        else               asm volatile("s_waitcnt vmcnt(0)" ::: "memory");
        __builtin_amdgcn_s_barrier();
        __builtin_amdgcn_sched_barrier(0);
        if (t + 3 < NT) stage(t + 3);
        bf16x8 af[8], bf[4];
#pragma unroll
        for (int i = 0; i < 8; ++i)
            af[i] = *(const bf16x8*)&As[s][wm * 128 + i * 16 + row16][quad * 8];
#pragma unroll
        for (int j = 0; j < 4; ++j)
            bf[j] = *(const bf16x8*)&Bs[s][wn * 64 + j * 16 + row16][quad * 8];
        __builtin_amdgcn_s_setprio(1);
#pragma unroll
        for (int i = 0; i < 8; ++i)
#pragma unroll
            for (int j = 0; j < 4; ++j)
                acc[i][j] = __builtin_amdgcn_mfma_f32_16x16x32_bf16(af[i], bf[j], acc[i][j], 0, 0, 0);
        __builtin_amdgcn_s_setprio(0);
    }

    const int col0 = bn + wn * 64 + row16;
    const int row0 = bm + wm * 128 + quad * 4;
#pragma unroll
    for (int i = 0; i < 8; ++i)
#pragma unroll
        for (int j = 0; j < 4; ++j)
#pragma unroll
            for (int rg = 0; rg < 4; ++rg)
                stc(C, (size_t)(row0 + i * 16 + rg) * N + col0 + j * 16, acc[i][j][rg]);
}

// Fallback GEMM (fp32 or bf16 inputs via ld8 staging). Used when ws is small.
template <typename TA, typename TB, typename TC>
__global__ __launch_bounds__(256) void gemm_bt(const TA* __restrict__ A,
                                               const TB* __restrict__ Bt,
                                               TC* __restrict__ C,
                                               int M, int N, int K, int lda) {
    __shared__ __align__(16) __hip_bfloat16 As[128][32];
    __shared__ __align__(16) __hip_bfloat16 Bs[128][32];
    const int bn = blockIdx.x * 128, bm = blockIdx.y * 128;
    const int tid = threadIdx.x, wave = tid >> 6, lane = tid & 63;
    const int wm = (wave >> 1) * 64, wn = (wave & 1) * 64;
    const int row16 = lane & 15, quad = lane >> 4;
    const int arow = tid >> 2;
    const int acol = (tid & 3) * 8;

    f32x4 acc[4][4] = {};

    for (int kt = 0; kt < K; kt += 32) {
        __syncthreads();
#pragma unroll
        for (int it = 0; it < 2; ++it) {
            int r = arow + it * 64;
            *(uint4*)&As[r][acol] = ld8(&A[(size_t)(bm + r) * lda + kt + acol]);
            *(uint4*)&Bs[r][acol] = ld8(&Bt[(size_t)(bn + r) * K + kt + acol]);
        }
        __syncthreads();
        bf16x8 af[4], bf[4];
#pragma unroll
        for (int i = 0; i < 4; ++i) af[i] = *(const bf16x8*)&As[wm + i * 16 + row16][quad * 8];
#pragma unroll
        for (int j = 0; j < 4; ++j) bf[j] = *(const bf16x8*)&Bs[wn + j * 16 + row16][quad * 8];
#pragma unroll
        for (int i = 0; i < 4; ++i)
#pragma unroll
            for (int j = 0; j < 4; ++j)
                acc[i][j] = __builtin_amdgcn_mfma_f32_16x16x32_bf16(af[i], bf[j], acc[i][j], 0, 0, 0);
    }
    const int col0 = bn + wn + row16;
    const int row0 = bm + wm + quad * 4;
#pragma unroll
    for (int i = 0; i < 4; ++i)
#pragma unroll
        for (int j = 0; j < 4; ++j)
#pragma unroll
            for (int rg = 0; rg < 4; ++rg)
                stc(C, (size_t)(row0 + i * 16 + rg) * N + col0 + j * 16, acc[i][j][rg]);
}

// In-place RoPE on the Q and K thirds of proj[MTOT][QKV]. position = row % SEQ.
// Q rows additionally pre-scaled by 1/sqrt(HD) so attn skips the score scaling.
__global__ __launch_bounds__(256) void rope_kernel(__hip_bfloat16* __restrict__ proj) {
    int t = blockIdx.x * 256 + threadIdx.x;
    int j = t & 63;
    int head = (t >> 6) & 31;
    int mat = (t >> 11) & 1;
    int row = t >> 12;
    int pos = row & (SEQ - 1);
    float invf = __expf(-(float)j * 0.14391156514261f);   // 10000^(-j/64)
    float ang = (float)pos * invf;
    float rev = ang * 0.15915494309189535f;               // range-reduce for v_sin/v_cos
    rev -= floorf(rev);
    float arad = rev * 6.283185307179586f;
    float sn = __sinf(arad);
    float cs = __cosf(arad);
    if (mat == 0) {                     // Q third: fold in 1/sqrt(128)
        sn *= 0.08838834764831845f;
        cs *= 0.08838834764831845f;
    }
    size_t base = (size_t)row * QKV + mat * HIDDEN + head * HD + j;
    float x1 = __bfloat162float(proj[base]);
    float x2 = __bfloat162float(proj[base + 64]);
    proj[base]      = __float2bfloat16(x1 * cs - x2 * sn);
    proj[base + 64] = __float2bfloat16(x2 * cs + x1 * sn);
}

// One-shot V transpose: proj V-third [b][s][h*128+d] -> vtg[(b*32+h)][d][s].
__global__ __launch_bounds__(256) void transpose_v(const __hip_bfloat16* __restrict__ proj,
                                                   __hip_bfloat16* __restrict__ vtg) {
    __shared__ __hip_bfloat16 Ls[64][132];
    const int st = blockIdx.x, bh = blockIdx.y;
    const int b = bh >> 5, h = bh & 31;
    const int s0 = st << 6;
    const int tid = threadIdx.x;
    const __hip_bfloat16* vb = proj + (size_t)b * SEQ * QKV + 2 * HIDDEN + h * HD;
    for (int i = tid; i < 1024; i += 256) {
        int r = i >> 4, c = (i & 15) << 3;
        uint4 raw = *(const uint4*)&vb[(size_t)(s0 + r) * QKV + c];
        *(uint2*)&Ls[r][c]     = make_uint2(raw.x, raw.y);
        *(uint2*)&Ls[r][c + 4] = make_uint2(raw.z, raw.w);
    }
    __syncthreads();
    __hip_bfloat16* ob = vtg + (size_t)bh * HD * SEQ + s0;
    for (int t = tid; t < 1024; t += 256) {
        int d = t >> 3, sc = (t & 7) << 3;
        __hip_bfloat16 tmp[8];
#pragma unroll
        for (int x = 0; x < 8; ++x) tmp[x] = Ls[sc + x][d];
        *(uint4*)&ob[(size_t)d * SEQ + sc] = *(uint4*)tmp;
    }
}

// MFMA flash attention. Block = 128 q-rows x (b,h); 4 waves x 32 q-rows each.
// Requires gridDim.x == SEQ/128 == 16. Two barriers per 64-key tile; the Ps
// LDS buffer is strictly per-wave so no barrier is needed between its write
// and read (in-wave LDS DS ops execute in program order).
__global__ __launch_bounds__(256) void attn_mfma(__hip_bfloat16* __restrict__ proj,
                                                 const __hip_bfloat16* __restrict__ vtg) {
    __shared__ __align__(16) __hip_bfloat16 Ks[64][136];   // 64 keys x 128 d
    __shared__ __align__(16) __hip_bfloat16 Vs[128][72];   // 128 d x 64 keys
    __shared__ __align__(16) __hip_bfloat16 Ps[4][32][72]; // per-wave P tile
    // XCD-chunked swizzle (bijective: nwg=1024, %8==0): each XCD owns 8 whole
    // heads so the active head's K/V (1 MB) stays resident in its 4 MiB L2.
    const int nwg = gridDim.x * gridDim.y;
    const int f  = blockIdx.y * gridDim.x + blockIdx.x;
    const int f2 = (f & 7) * (nwg >> 3) + (f >> 3);
    const int qt = f2 & 15;            // gridDim.x == 16
    const int bh = f2 >> 4;
    const int b = bh >> 5, h = bh & 31;
    const int q0 = qt << 7;
    const int tid = threadIdx.x, wave = tid >> 6, lane = tid & 63;
    const int row16 = lane & 15, quad = lane >> 4;

    __hip_bfloat16* qb = proj + (size_t)b * SEQ * QKV + h * HD;
    const __hip_bfloat16* kb = qb + HIDDEN;
    const __hip_bfloat16* vp = vtg + (size_t)bh * HD * SEQ;

    const int wbase = q0 + wave * 32;

    bf16x8 qf[2][4];
#pragma unroll
    for (int qr = 0; qr < 2; ++qr) {
        const __hip_bfloat16* qrow = qb + (size_t)(wbase + qr * 16 + row16) * QKV + quad * 8;
#pragma unroll
        for (int s = 0; s < 4; ++s) qf[qr][s] = *(const bf16x8*)(qrow + s * 32);
    }

    f32x4 oa[2][8] = {};
    float m_i[2][4], l_i[2][4];
#pragma unroll
    for (int qr = 0; qr < 2; ++qr)
#pragma unroll
        for (int r = 0; r < 4; ++r) { m_i[qr][r] = -3.0e38f; l_i[qr][r] = 0.f; }

    const int ktmax = 2 * qt + 1;
    for (int kt = 0; kt <= ktmax; ++kt) {
        const int k0 = kt << 6;
        __syncthreads();
        for (int i = tid; i < 1024; i += 256) {
            int r = i >> 4, c = (i & 15) << 3;
            *(uint4*)&Ks[r][c] = *(const uint4*)&kb[(size_t)(k0 + r) * QKV + c];
        }
        for (int i = tid; i < 1024; i += 256) {
            int d = i >> 3, ko = (i & 7) << 3;
            *(uint4*)&Vs[d][ko] = *(const uint4*)&vp[(size_t)d * SEQ + k0 + ko];
        }
        __syncthreads();
        // Both barriers of this iteration are done; waves whose 32 rows are
        // entirely above this key tile skip the compute (wave-uniform).
        if (k0 > wbase + 31) continue;

        // S = Q K^T  (Q pre-scaled by 1/sqrt(d) in rope_kernel)
        f32x4 sf[2][4] = {};
#pragma unroll
        for (int nt = 0; nt < 4; ++nt) {
            bf16x8 kf[4];
#pragma unroll
            for (int ks = 0; ks < 4; ++ks)
                kf[ks] = *(const bf16x8*)&Ks[nt * 16 + row16][ks * 32 + quad * 8];
#pragma unroll
            for (int qr = 0; qr < 2; ++qr)
#pragma unroll
                for (int ks = 0; ks < 4; ++ks)
                    sf[qr][nt] = __builtin_amdgcn_mfma_f32_16x16x32_bf16(qf[qr][ks], kf[ks], sf[qr][nt], 0, 0, 0);
        }
        if (k0 + 63 > wbase) {          // diagonal region: causal mask
#pragma unroll
            for (int qr = 0; qr < 2; ++qr)
#pragma unroll
                for (int nt = 0; nt < 4; ++nt) {
                    int key = k0 + nt * 16 + row16;
#pragma unroll
                    for (int rg = 0; rg < 4; ++rg)
                        if (key > wbase + qr * 16 + quad * 4 + rg) sf[qr][nt][rg] = -3.0e38f;
                }
        }
        // online softmax, per 16-row fragment
#pragma unroll
        for (int qr = 0; qr < 2; ++qr) {
            float alpha[4], rs[4];
#pragma unroll
            for (int rg = 0; rg < 4; ++rg) {
                float mx = fmaxf(fmaxf(sf[qr][0][rg], sf[qr][1][rg]), fmaxf(sf[qr][2][rg], sf[qr][3][rg]));
#pragma unroll
                for (int off = 8; off > 0; off >>= 1) mx = fmaxf(mx, __shfl_xor(mx, off));
                float mn = fmaxf(m_i[qr][rg], mx);
                alpha[rg] = __expf(m_i[qr][rg] - mn);
                m_i[qr][rg] = mn;
                rs[rg] = 0.f;
            }
#pragma unroll
            for (int nt = 0; nt < 4; ++nt)
#pragma unroll
                for (int rg = 0; rg < 4; ++rg) {
                    float p = __expf(sf[qr][nt][rg] - m_i[qr][rg]);
                    rs[rg] += p;
                    Ps[wave][qr * 16 + quad * 4 + rg][nt * 16 + row16] = __float2bfloat16(p);
                }
#pragma unroll
            for (int rg = 0; rg < 4; ++rg) {
#pragma unroll
                for (int off = 8; off > 0; off >>= 1) rs[rg] += __shfl_xor(rs[rg], off);
                l_i[qr][rg] = l_i[qr][rg] * alpha[rg] + rs[rg];
            }
#pragma unroll
            for (int dt = 0; dt < 8; ++dt)
#pragma unroll
                for (int rg = 0; rg < 4; ++rg) oa[qr][dt][rg] *= alpha[rg];
        }
        __builtin_amdgcn_wave_barrier();   // compile-time order: Ps writes before reads
        bf16x8 pf[2][2];
#pragma unroll
        for (int qr = 0; qr < 2; ++qr) {
            pf[qr][0] = *(const bf16x8*)&Ps[wave][qr * 16 + row16][quad * 8];
            pf[qr][1] = *(const bf16x8*)&Ps[wave][qr * 16 + row16][32 + quad * 8];
        }
#pragma unroll
        for (int dt = 0; dt < 8; ++dt) {
            bf16x8 v0 = *(const bf16x8*)&Vs[dt * 16 + row16][quad * 8];
            bf16x8 v1 = *(const bf16x8*)&Vs[dt * 16 + row16][32 + quad * 8];
#pragma unroll
            for (int qr = 0; qr < 2; ++qr) {
                oa[qr][dt] = __builtin_amdgcn_mfma_f32_16x16x32_bf16(pf[qr][0], v0, oa[qr][dt], 0, 0, 0);
                oa[qr][dt] = __builtin_amdgcn_mfma_f32_16x16x32_bf16(pf[qr][1], v1, oa[qr][dt], 0, 0, 0);
            }
        }
    }
#pragma unroll
    for (int qr = 0; qr < 2; ++qr)
#pragma unroll
        for (int rg = 0; rg < 4; ++rg) {
            float inv = 1.0f / l_i[qr][rg];
            __hip_bfloat16* orow = qb + (size_t)(wbase + qr * 16 + quad * 4 + rg) * QKV;
#pragma unroll
            for (int dt = 0; dt < 8; ++dt)
                orow[dt * 16 + row16] = __float2bfloat16(oa[qr][dt][rg] * inv);
        }
}

extern "C" void kernel_launch(void* const* d_in, const int* in_sizes, int n_in,
                              void* d_out, int out_size, void* d_ws, size_t ws_size,
                              hipStream_t stream) {
    const float* hs = (const float*)d_in[0];
    const float* Wp = (const float*)d_in[3];
    const float* Wo = (const float*)d_in[4];
    float* out = (float*)d_out;

    const size_t SZ_PROJ = (size_t)MTOT * QKV;      // bf16 elems
    const size_t SZ_H    = (size_t)MTOT * HIDDEN;
    const size_t SZ_WP   = (size_t)QKV * HIDDEN;
    const size_t need = (SZ_PROJ + SZ_H + SZ_WP + SZ_H) * sizeof(__hip_bfloat16);  // 256 MiB

    __hip_bfloat16* proj = (__hip_bfloat16*)d_ws;

    if (ws_size >= need) {
        // [proj][hsb][Wpb][Wob]; vtg aliases the (dead-after-GEMM1) hsb region.
        __hip_bfloat16* hsb = proj + SZ_PROJ;
        __hip_bfloat16* Wpb = hsb + SZ_H;
        __hip_bfloat16* Wob = Wpb + SZ_WP;
        __hip_bfloat16* vtg = hsb;   // 33.6 MB, fits in hsb+Wpb (134 MB)

        cvt_bf16<<<dim3(SZ_H / 8 / 256), dim3(256), 0, stream>>>(hs, hsb, SZ_H / 8);
        cvt_bf16<<<dim3(SZ_WP / 8 / 256), dim3(256), 0, stream>>>(Wp, Wpb, SZ_WP / 8);
        cvt_bf16<<<dim3(SZ_H / 8 / 256), dim3(256), 0, stream>>>(Wo, Wob, SZ_H / 8);
        gemm_256<<<dim3(QKV / 256, MTOT / 256), dim3(512), 0, stream>>>(hsb, Wpb, proj, MTOT, QKV, HIDDEN, HIDDEN);
        rope_kernel<<<dim3((MTOT * 2 * NH * 64) / 256), dim3(256), 0, stream>>>(proj);
        transpose_v<<<dim3(SEQ / 64, BATCH * NH), dim3(256), 0, stream>>>(proj, vtg);
        attn_mfma<<<dim3(SEQ / 128, BATCH * NH), dim3(256), 0, stream>>>(proj, vtg);
        gemm_256<<<dim3(HIDDEN / 256, MTOT / 256), dim3(512), 0, stream>>>(proj, Wob, out, MTOT, HIDDEN, HIDDEN, QKV);
    } else {
        // proven 128-MiB fallback (round-4 path)
        __hip_bfloat16* vtg = proj + SZ_PROJ;
        gemm_bt<<<dim3(QKV / 128, MTOT / 128), dim3(256), 0, stream>>>(hs, Wp, proj, MTOT, QKV, HIDDEN, HIDDEN);
        rope_kernel<<<dim3((MTOT * 2 * NH * 64) / 256), dim3(256), 0, stream>>>(proj);
        transpose_v<<<dim3(SEQ / 64, BATCH * NH), dim3(256), 0, stream>>>(proj, vtg);
        attn_mfma<<<dim3(SEQ / 128, BATCH * NH), dim3(256), 0, stream>>>(proj, vtg);
        gemm_bt<<<dim3(HIDDEN / 128, MTOT / 128), dim3(256), 0, stream>>>(proj, Wo, out, MTOT, HIDDEN, HIDDEN, QKV);
    }
}